// Round 11
// baseline (26.710 us; speedup 1.0000x reference)
//
#include <hip/hip_runtime.h>

#define NCH   30            // 2*5 + 20
#define NCONF 98
#define IMGF  1470          // floats per image
#define PAIR4 735           // float4 per image pair (11760 B, 16B-aligned)
#define LCf 5.0f
#define LNf 0.5f

#define AS1 __attribute__((address_space(1)))
#define AS3 __attribute__((address_space(3)))

// Per-image, per-lane partial loss. All 64 lanes dense; quad (4 lanes) per target.
__device__ __forceinline__ float img_partial(const float* __restrict__ img,
                                             float4 bx, int lab,
                                             volatile unsigned char* sm,
                                             int lane, int t, int q)
{
    // ---- no-obj conf^2 partial: slots lane and lane+64 ----
    float ns;
    {
        int c = lane >> 1, b = lane & 1;
        float cf = img[c * NCH + b * 5 + 4];
        ns = cf * cf;
        if (lane < NCONF - 64) {
            int s2 = lane + 64;
            int c2 = s2 >> 1, b2 = s2 & 1;
            float cf2 = img[c2 * NCH + b2 * 5 + 4];
            ns += cf2 * cf2;
        }
    }

    const float tx = bx.x, ty = bx.y, tw = bx.z, th = bx.w;
    const float fx = tx * 7.0f, fy = ty * 7.0f;
    const int gxi = (int)fx, gyi = (int)fy;
    const float offx = fx - (float)gxi;
    const float offy = fy - (float)gyi;
    const int cellIdx = gyi * 7 + gxi;
    const float* cell = img + cellIdx * NCH;

    // ---- q0/q1 compute their own box's IOU ----
    float px = 0.f, py = 0.f, pw = 0.f, ph = 0.f, pc = 0.f, iou_own = 0.f;
    if (q < 2) {
        float rx = cell[q * 5 + 0];
        float ry = cell[q * 5 + 1];
        pw       = cell[q * 5 + 2];
        ph       = cell[q * 5 + 3];
        pc       = cell[q * 5 + 4];
        px = (rx + (float)gxi) * (1.0f / 7.0f);
        py = (ry + (float)gyi) * (1.0f / 7.0f);

        float x1a = tx - tw * 0.5f, y1a = ty - th * 0.5f;
        float x2a = tx + tw * 0.5f, y2a = ty + th * 0.5f;
        float x1b = px - pw * 0.5f, y1b = py - ph * 0.5f;
        float x2b = px + pw * 0.5f, y2b = py + ph * 0.5f;
        float iw = fmaxf(fminf(x2a, x2b) - fmaxf(x1a, x1b), 0.0f);
        float ih = fmaxf(fminf(y2a, y2b) - fmaxf(y1a, y1b), 0.0f);
        float inter = iw * ih;
        float uni = tw * th + pw * ph - inter;
        iou_own = inter / fmaxf(uni, 1e-10f);
    }
    const float iou_other = __shfl_xor(iou_own, 1);
    int bestq = 0;
    if (q < 2) {
        float i0 = (q == 0) ? iou_own   : iou_other;
        float i1 = (q == 0) ? iou_other : iou_own;
        bestq = (i1 >= i0) ? 1 : 0;      // ties -> last box (ref semantics)
    }
    const int best = __shfl(bestq, lane & ~3);    // broadcast from quad's q0
    const int s = cellIdx * 2 + best;             // marked slot id

    // ---- box + obj loss on the owning lane ----
    float contrib = 0.0f;
    const float eps = 1e-6f;
    if (q == best) {
        float dx = px - offx, dy = py - offy;
        float dw = sqrtf(fmaxf(pw, eps)) - sqrtf(fmaxf(tw, eps));
        float dh = sqrtf(fmaxf(ph, eps)) - sqrtf(fmaxf(th, eps));
        float box_l = dx * dx + dy * dy + dw * dw + dh * dh;
        float obj_l = (pc - 1.0f) * (pc - 1.0f);
        contrib = LCf * box_l + obj_l;
    }

    // ---- dedup via LDS mask: one winner per distinct slot (wave-local) ----
    if (q == best) sm[s] = (unsigned char)lane;
    asm volatile("s_waitcnt lgkmcnt(0)" ::: "memory");
    __builtin_amdgcn_sched_barrier(0);
    const bool winner = (q == best) && (sm[s] == (unsigned char)lane);
    const unsigned long long bal = __ballot(winner);
    const int mc = __popcll(bal);                 // wave-uniform distinct count
    const float ms = winner ? pc * pc : 0.0f;

    // ---- class loss: 5 classes per lane, quad reductions ----
    {
        float cv[5];
        #pragma unroll
        for (int i = 0; i < 5; ++i) cv[i] = cell[10 + q * 5 + i];
        float m = fmaxf(fmaxf(fmaxf(cv[0], cv[1]), fmaxf(cv[2], cv[3])), cv[4]);
        m = fmaxf(m, __shfl_xor(m, 1));
        m = fmaxf(m, __shfl_xor(m, 2));
        float esum = 0.f, e2 = 0.f, elab = 0.f;
        #pragma unroll
        for (int i = 0; i < 5; ++i) {
            float e = __expf(cv[i] - m);
            esum += e; e2 += e * e;
            if (q * 5 + i == lab) elab = e;
        }
        esum += __shfl_xor(esum, 1);  esum += __shfl_xor(esum, 2);
        e2   += __shfl_xor(e2,   1);  e2   += __shfl_xor(e2,   2);
        elab += __shfl_xor(elab, 1);  elab += __shfl_xor(elab, 2);
        if (q == 0) {
            float inv = 1.0f / esum;
            contrib += e2 * inv * inv - 2.0f * elab * inv + 1.0f;
        }
    }

    // per-lane fold: division by wave-uniform (98-mc) distributes over the sum
    const float invDen = 1.0f / (98.0f - (float)mc);
    return contrib + LNf * (ns - ms) * invDen;
}

// 128-thread block = 2 independent waves; each wave owns one image PAIR.
// Split-wait pipeline: compute img0 under img1's in-flight staging loads.
__global__ __launch_bounds__(128) void yolo_loss_kernel(
    const float* __restrict__ outputs,
    const float* __restrict__ boxes,
    const int*   __restrict__ labels,
    float*       __restrict__ pair_sum)
{
    const int tid  = threadIdx.x;
    const int wave = tid >> 6;
    const int lane = tid & 63;
    const int t    = lane >> 2;      // target 0..15
    const int q    = lane & 3;       // quad role
    const int n0   = (blockIdx.x * 2 + wave) * 2;   // this wave's first image

    __shared__ float         s_buf[2 * 2 * IMGF];   // 23520 B (2 pairs)
    __shared__ unsigned char s_m[2][2][112];        // per-wave, per-image mask

    // target data loads first (oldest in vmcnt queue; compiler also self-waits)
    const float4* bx4 = reinterpret_cast<const float4*>(boxes);
    const float4 bx0 = bx4[(size_t)n0 * 16 + t];
    const float4 bx1 = bx4[(size_t)(n0 + 1) * 16 + t];
    const int   lab0 = labels[(size_t)n0 * 16 + t] - 1;
    const int   lab1 = labels[(size_t)(n0 + 1) * 16 + t] - 1;
    __builtin_amdgcn_sched_barrier(0);

    // ---- stage this wave's pair: 735 float4 = 11 full rounds + 31-lane tail ----
    // rounds 0..5 (384 float4 = 6144 B) fully cover img0 (5880 B).
    const float4* out4 = reinterpret_cast<const float4*>(outputs);
    const size_t pbase = (size_t)(n0 >> 1) * PAIR4;
    char* wbase = (char*)s_buf + (size_t)wave * (PAIR4 * 16);
    #pragma unroll
    for (int k = 0; k < 6; ++k) {
        __builtin_amdgcn_global_load_lds(
            (const AS1 void*)(out4 + pbase + k * 64 + lane),
            (AS3 void*)(wbase + (size_t)k * 64 * 16), 16, 0, 0);
    }
    #pragma unroll
    for (int k = 6; k < 11; ++k) {
        __builtin_amdgcn_global_load_lds(
            (const AS1 void*)(out4 + pbase + k * 64 + lane),
            (AS3 void*)(wbase + (size_t)k * 64 * 16), 16, 0, 0);
    }
    if (lane < PAIR4 - 704) {        // tail: 31 lanes
        __builtin_amdgcn_global_load_lds(
            (const AS1 void*)(out4 + pbase + 704 + lane),
            (AS3 void*)(wbase + (size_t)704 * 16), 16, 0, 0);
    }

    const float* img0 = s_buf + (size_t)wave * 2 * IMGF;
    const float* img1 = img0 + IMGF;

    // wait only the 6 oldest staging loads (img0); img1's 6 stay in flight
    asm volatile("s_waitcnt vmcnt(6)" ::: "memory");
    __builtin_amdgcn_sched_barrier(0);
    float v = img_partial(img0, bx0, lab0, s_m[wave][0], lane, t, q);

    asm volatile("s_waitcnt vmcnt(0)" ::: "memory");
    __builtin_amdgcn_sched_barrier(0);
    v += img_partial(img1, bx1, lab1, s_m[wave][1], lane, t, q);

    #pragma unroll
    for (int off = 32; off > 0; off >>= 1) v += __shfl_xor(v, off);
    if (lane == 0) pair_sum[blockIdx.x * 2 + wave] = v;
}

__global__ __launch_bounds__(256) void reduce_mean_kernel(
    const float* __restrict__ pair_sum, float* __restrict__ out, int np, int N)
{
    __shared__ double sd[4];
    double acc = 0.0;
    const float4* p4 = reinterpret_cast<const float4*>(pair_sum);
    for (int i = threadIdx.x; i < np / 4; i += 256) {
        float4 v = p4[i];
        acc += (double)v.x + (double)v.y + (double)v.z + (double)v.w;
    }
    #pragma unroll
    for (int off = 32; off > 0; off >>= 1) acc += __shfl_xor(acc, off);
    if ((threadIdx.x & 63) == 0) sd[threadIdx.x >> 6] = acc;
    __syncthreads();
    if (threadIdx.x == 0)
        out[0] = (float)(((sd[0] + sd[1]) + (sd[2] + sd[3])) / (double)N);
}

extern "C" void kernel_launch(void* const* d_in, const int* in_sizes, int n_in,
                              void* d_out, int out_size, void* d_ws, size_t ws_size,
                              hipStream_t stream) {
    const float* outputs = (const float*)d_in[0];
    const float* boxes   = (const float*)d_in[1];
    const int*   labels  = (const int*)d_in[2];
    float* out = (float*)d_out;

    const int N  = in_sizes[0] / IMGF;  // 16384 images
    const int nb = N / 4;               // 4096 blocks (2 waves x 1 pair each)
    const int np = nb * 2;              // 8192 pair sums
    float* pair_sum = (float*)d_ws;

    yolo_loss_kernel<<<nb, 128, 0, stream>>>(outputs, boxes, labels, pair_sum);
    reduce_mean_kernel<<<1, 256, 0, stream>>>(pair_sum, out, np, N);
}

// Round 12
// 24.260 us; speedup vs baseline: 1.1010x; 1.1010x over previous
//
#include <hip/hip_runtime.h>

#define NCH   30            // 2*5 + 20
#define NCONF 98
#define IMGF  1470          // floats per image (5880 B; 16B-aligned only when n even)
#define LCf 5.0f
#define LNf 0.5f

#define AS1 __attribute__((address_space(1)))
#define AS3 __attribute__((address_space(3)))

// Per-image, per-lane partial loss (round-10 proven body, cf1 preloaded).
__device__ __forceinline__ float img_partial(const float* __restrict__ img,
                                             float4 bx, int lab,
                                             volatile unsigned char* sm,
                                             int lane, int t, int q, float cf1)
{
    // ---- no-obj conf^2 partial: slot lane (preloaded cf1) + slot lane+64 ----
    float ns = cf1 * cf1;
    if (lane < NCONF - 64) {
        int s2 = lane + 64;
        int c2 = s2 >> 1, b2 = s2 & 1;
        float cf2 = img[c2 * NCH + b2 * 5 + 4];
        ns += cf2 * cf2;
    }

    const float tx = bx.x, ty = bx.y, tw = bx.z, th = bx.w;
    const float fx = tx * 7.0f, fy = ty * 7.0f;
    const int gxi = (int)fx, gyi = (int)fy;
    const float offx = fx - (float)gxi;
    const float offy = fy - (float)gyi;
    const int cellIdx = gyi * 7 + gxi;
    const float* cell = img + cellIdx * NCH;

    // ---- q0/q1 compute their own box's IOU ----
    float px = 0.f, py = 0.f, pw = 0.f, ph = 0.f, pc = 0.f, iou_own = 0.f;
    if (q < 2) {
        float rx = cell[q * 5 + 0];
        float ry = cell[q * 5 + 1];
        pw       = cell[q * 5 + 2];
        ph       = cell[q * 5 + 3];
        pc       = cell[q * 5 + 4];
        px = (rx + (float)gxi) * (1.0f / 7.0f);
        py = (ry + (float)gyi) * (1.0f / 7.0f);

        float x1a = tx - tw * 0.5f, y1a = ty - th * 0.5f;
        float x2a = tx + tw * 0.5f, y2a = ty + th * 0.5f;
        float x1b = px - pw * 0.5f, y1b = py - ph * 0.5f;
        float x2b = px + pw * 0.5f, y2b = py + ph * 0.5f;
        float iw = fmaxf(fminf(x2a, x2b) - fmaxf(x1a, x1b), 0.0f);
        float ih = fmaxf(fminf(y2a, y2b) - fmaxf(y1a, y1b), 0.0f);
        float inter = iw * ih;
        float uni = tw * th + pw * ph - inter;
        iou_own = inter / fmaxf(uni, 1e-10f);
    }
    const float iou_other = __shfl_xor(iou_own, 1);
    int bestq = 0;
    if (q < 2) {
        float i0 = (q == 0) ? iou_own   : iou_other;
        float i1 = (q == 0) ? iou_other : iou_own;
        bestq = (i1 >= i0) ? 1 : 0;      // ties -> last box (ref semantics)
    }
    const int best = __shfl(bestq, lane & ~3);    // broadcast from quad's q0
    const int s = cellIdx * 2 + best;             // marked slot id

    // ---- box + obj loss on the owning lane ----
    float contrib = 0.0f;
    const float eps = 1e-6f;
    if (q == best) {
        float dx = px - offx, dy = py - offy;
        float dw = sqrtf(fmaxf(pw, eps)) - sqrtf(fmaxf(tw, eps));
        float dh = sqrtf(fmaxf(ph, eps)) - sqrtf(fmaxf(th, eps));
        float box_l = dx * dx + dy * dy + dw * dw + dh * dh;
        float obj_l = (pc - 1.0f) * (pc - 1.0f);
        contrib = LCf * box_l + obj_l;
    }

    // ---- dedup via LDS mask: one winner per distinct slot (wave-local) ----
    if (q == best) sm[s] = (unsigned char)lane;
    asm volatile("s_waitcnt lgkmcnt(0)" ::: "memory");
    __builtin_amdgcn_sched_barrier(0);
    const bool winner = (q == best) && (sm[s] == (unsigned char)lane);
    const unsigned long long bal = __ballot(winner);
    const int mc = __popcll(bal);                 // wave-uniform distinct count
    const float ms = winner ? pc * pc : 0.0f;

    // ---- class loss: 5 classes per lane, quad reductions ----
    {
        float cv[5];
        #pragma unroll
        for (int i = 0; i < 5; ++i) cv[i] = cell[10 + q * 5 + i];
        float m = fmaxf(fmaxf(fmaxf(cv[0], cv[1]), fmaxf(cv[2], cv[3])), cv[4]);
        m = fmaxf(m, __shfl_xor(m, 1));
        m = fmaxf(m, __shfl_xor(m, 2));
        float esum = 0.f, e2 = 0.f, elab = 0.f;
        #pragma unroll
        for (int i = 0; i < 5; ++i) {
            float e = __expf(cv[i] - m);
            esum += e; e2 += e * e;
            if (q * 5 + i == lab) elab = e;
        }
        esum += __shfl_xor(esum, 1);  esum += __shfl_xor(esum, 2);
        e2   += __shfl_xor(e2,   1);  e2   += __shfl_xor(e2,   2);
        elab += __shfl_xor(elab, 1);  elab += __shfl_xor(elab, 2);
        if (q == 0) {
            float inv = 1.0f / esum;
            contrib += e2 * inv * inv - 2.0f * elab * inv + 1.0f;
        }
    }

    // per-lane fold: division by wave-uniform (98-mc) distributes over the sum
    const float invDen = 1.0f / (98.0f - (float)mc);
    return contrib + LNf * (ns - ms) * invDen;
}

// 256 threads = 4 fully independent waves; wave w owns image bid*4+w.
// Wave-local staging (parity-split widths), wave-local vmcnt waits; the only
// s_barrier is the trivial end-of-block 4-way combine.
__global__ __launch_bounds__(256) void yolo_loss_kernel(
    const float* __restrict__ outputs,
    const float* __restrict__ boxes,
    const int*   __restrict__ labels,
    float*       __restrict__ block_sum)
{
    const int tid  = threadIdx.x;
    const int wave = tid >> 6;
    const int lane = tid & 63;
    const int t    = lane >> 2;      // target 0..15
    const int q    = lane & 3;       // quad role
    const int n    = blockIdx.x * 4 + wave;   // parity(n) == parity(wave)

    __shared__ float         s_img[4 * IMGF];   // 23520 B
    __shared__ unsigned char s_m[4][112];
    __shared__ float         s_ws[4];

    // target data loads (anywhere in the VMEM queue; wait math tolerates it)
    const float4 bx = reinterpret_cast<const float4*>(boxes)[(size_t)n * 16 + t];
    const int   lab = labels[(size_t)n * 16 + t] - 1;

    // ---- wave-local staging: 7 insts, parity-split for 16B alignment ----
    // odd n : [head 8B w4 x2lanes] + 6 x w16 rounds over (gsrc+2), base lds+8
    // even n: [tail 8B w4 x2lanes] + 6 x w16 rounds over gsrc,      base lds+0
    const float* gsrc = outputs + (size_t)n * IMGF;
    char* wbase = (char*)&s_img[wave * IMGF];
    const int odd = wave & 1;
    {
        // small 8B piece (2 lanes active)
        const float* sgp = odd ? gsrc : (gsrc + IMGF - 2);
        char*        slp = odd ? wbase : (wbase + (size_t)(IMGF - 2) * 4);
        if (lane < 2) {
            __builtin_amdgcn_global_load_lds((const AS1 void*)(sgp + lane),
                                             (AS3 void*)slp, 4, 0, 0);
        }
        // 367 float4 main body, 16B-aligned both sides
        const float4* g4 = reinterpret_cast<const float4*>(gsrc + (odd ? 2 : 0));
        char* l4 = wbase + (odd ? 8 : 0);
        #pragma unroll
        for (int k = 0; k < 5; ++k) {
            __builtin_amdgcn_global_load_lds(
                (const AS1 void*)(g4 + k * 64 + lane),
                (AS3 void*)(l4 + (size_t)k * 1024), 16, 0, 0);
        }
        if (lane < 367 - 320) {      // round 5 tail: 47 lanes
            __builtin_amdgcn_global_load_lds(
                (const AS1 void*)(g4 + 320 + lane),
                (AS3 void*)(l4 + (size_t)5 * 1024), 16, 0, 0);
        }
    }

    const float* img = &s_img[wave * IMGF];

    // split wait: oldest 7 of 9 VMEM ops done -> small + rounds 0..3 landed in
    // ANY compiler placement of bx/lab => floats 0..959 (cells 0..31) valid.
    asm volatile("s_waitcnt vmcnt(2)" ::: "memory");
    __builtin_amdgcn_sched_barrier(0);
    const float cf1 = img[(lane >> 1) * NCH + (lane & 1) * 5 + 4]; // slot=lane

    // full wave-local wait for the rest (also covers bx/lab)
    asm volatile("s_waitcnt vmcnt(0)" ::: "memory");
    __builtin_amdgcn_sched_barrier(0);

    float v = img_partial(img, bx, lab, s_m[wave], lane, t, q, cf1);

    #pragma unroll
    for (int off = 32; off > 0; off >>= 1) v += __shfl_xor(v, off);
    if (lane == 0) s_ws[wave] = v;
    __syncthreads();                 // end-of-block combine only
    if (tid == 0)
        block_sum[blockIdx.x] = (s_ws[0] + s_ws[1]) + (s_ws[2] + s_ws[3]);
}

__global__ __launch_bounds__(256) void reduce_mean_kernel(
    const float* __restrict__ block_sum, float* __restrict__ out, int nb, int N)
{
    __shared__ double sd[4];
    double acc = 0.0;
    const float4* p4 = reinterpret_cast<const float4*>(block_sum);
    for (int i = threadIdx.x; i < nb / 4; i += 256) {
        float4 v = p4[i];
        acc += (double)v.x + (double)v.y + (double)v.z + (double)v.w;
    }
    #pragma unroll
    for (int off = 32; off > 0; off >>= 1) acc += __shfl_xor(acc, off);
    if ((threadIdx.x & 63) == 0) sd[threadIdx.x >> 6] = acc;
    __syncthreads();
    if (threadIdx.x == 0)
        out[0] = (float)(((sd[0] + sd[1]) + (sd[2] + sd[3])) / (double)N);
}

extern "C" void kernel_launch(void* const* d_in, const int* in_sizes, int n_in,
                              void* d_out, int out_size, void* d_ws, size_t ws_size,
                              hipStream_t stream) {
    const float* outputs = (const float*)d_in[0];
    const float* boxes   = (const float*)d_in[1];
    const int*   labels  = (const int*)d_in[2];
    float* out = (float*)d_out;

    const int N  = in_sizes[0] / IMGF;  // 16384 images
    const int nb = N / 4;               // 4096 blocks, 1 image per wave
    float* block_sum = (float*)d_ws;

    yolo_loss_kernel<<<nb, 256, 0, stream>>>(outputs, boxes, labels, block_sum);
    reduce_mean_kernel<<<1, 256, 0, stream>>>(block_sum, out, nb, N);
}

// Round 13
// 24.176 us; speedup vs baseline: 1.1048x; 1.0034x over previous
//
#include <hip/hip_runtime.h>

#define NCH   30            // 2*5 + 20
#define NCONF 98
#define IMGF  1470          // floats per image (5880 B)
#define LCf 5.0f
#define LNf 0.5f

#define AS1 __attribute__((address_space(1)))
#define AS3 __attribute__((address_space(3)))

// DPP cross-lane on the VALU pipe (not LDS). bound_ctrl=1: invalid -> 0.
template<int CTRL>
__device__ __forceinline__ float dppf(float v) {
    return __int_as_float(__builtin_amdgcn_update_dpp(
        0, __float_as_int(v), CTRL, 0xF, 0xF, true));
}
#define QP_XOR1 0xB1   // quad_perm(1,0,3,2)
#define QP_XOR2 0x4E   // quad_perm(2,3,0,1)
#define QP_B0   0x00   // quad_perm(0,0,0,0): broadcast quad lane0
#define ROW_ROR4 0x124
#define ROW_ROR8 0x128

__device__ __forceinline__ float rlane(float v, int k) {
    return __int_as_float(__builtin_amdgcn_readlane(__float_as_int(v), k));
}

// Per-image, per-lane partial loss. Quad (4 lanes) per target; zero shuffles.
__device__ __forceinline__ float img_partial(const float* __restrict__ img,
                                             float4 bx, int lab,
                                             volatile unsigned char* sm,
                                             int lane, int t, int q, float cf1)
{
    // ---- no-obj conf^2 partial: slot lane (preloaded) + slot lane+64 ----
    float ns = cf1 * cf1;
    if (lane < NCONF - 64) {
        int s2 = lane + 64;
        int c2 = s2 >> 1, b2 = s2 & 1;
        float cf2 = img[c2 * NCH + b2 * 5 + 4];
        ns += cf2 * cf2;
    }

    const float tx = bx.x, ty = bx.y, tw = bx.z, th = bx.w;
    const float fx = tx * 7.0f, fy = ty * 7.0f;
    const int gxi = (int)fx, gyi = (int)fy;
    const float offx = fx - (float)gxi;
    const float offy = fy - (float)gyi;
    const int cellIdx = gyi * 7 + gxi;
    const float* cell = img + cellIdx * NCH;

    // ---- q0/q1 compute their own box's IOU ----
    float px = 0.f, py = 0.f, pw = 0.f, ph = 0.f, pc = 0.f, iou_own = 0.f;
    if (q < 2) {
        float rx = cell[q * 5 + 0];
        float ry = cell[q * 5 + 1];
        pw       = cell[q * 5 + 2];
        ph       = cell[q * 5 + 3];
        pc       = cell[q * 5 + 4];
        px = (rx + (float)gxi) * (1.0f / 7.0f);
        py = (ry + (float)gyi) * (1.0f / 7.0f);

        float x1a = tx - tw * 0.5f, y1a = ty - th * 0.5f;
        float x2a = tx + tw * 0.5f, y2a = ty + th * 0.5f;
        float x1b = px - pw * 0.5f, y1b = py - ph * 0.5f;
        float x2b = px + pw * 0.5f, y2b = py + ph * 0.5f;
        float iw = fmaxf(fminf(x2a, x2b) - fmaxf(x1a, x1b), 0.0f);
        float ih = fmaxf(fminf(y2a, y2b) - fmaxf(y1a, y1b), 0.0f);
        float inter = iw * ih;
        float uni = tw * th + pw * ph - inter;
        iou_own = inter / fmaxf(uni, 1e-10f);
    }
    const float iou_other = dppf<QP_XOR1>(iou_own);   // all lanes active here
    int bestq = 0;
    if (q < 2) {
        float i0 = (q == 0) ? iou_own   : iou_other;
        float i1 = (q == 0) ? iou_other : iou_own;
        bestq = (i1 >= i0) ? 1 : 0;      // ties -> last box (ref semantics)
    }
    const int best = __builtin_amdgcn_update_dpp(0, bestq, QP_B0, 0xF, 0xF, true);
    const int s = cellIdx * 2 + best;                 // marked slot id

    // ---- box + obj loss on the owning lane ----
    float contrib = 0.0f;
    const float eps = 1e-6f;
    if (q == best) {
        float dx = px - offx, dy = py - offy;
        float dw = sqrtf(fmaxf(pw, eps)) - sqrtf(fmaxf(tw, eps));
        float dh = sqrtf(fmaxf(ph, eps)) - sqrtf(fmaxf(th, eps));
        float box_l = dx * dx + dy * dy + dw * dw + dh * dh;
        float obj_l = (pc - 1.0f) * (pc - 1.0f);
        contrib = LCf * box_l + obj_l;
    }

    // ---- dedup via LDS mask: one winner per distinct slot (wave-local) ----
    if (q == best) sm[s] = (unsigned char)lane;
    asm volatile("s_waitcnt lgkmcnt(0)" ::: "memory");
    __builtin_amdgcn_sched_barrier(0);
    const bool winner = (q == best) && (sm[s] == (unsigned char)lane);
    const unsigned long long bal = __ballot(winner);
    const int mc = __popcll(bal);                     // wave-uniform count
    const float ms = winner ? pc * pc : 0.0f;

    // ---- class loss: 5 classes per lane, quad reductions via DPP ----
    {
        float cv[5];
        #pragma unroll
        for (int i = 0; i < 5; ++i) cv[i] = cell[10 + q * 5 + i];
        float m = fmaxf(fmaxf(fmaxf(cv[0], cv[1]), fmaxf(cv[2], cv[3])), cv[4]);
        m = fmaxf(m, dppf<QP_XOR1>(m));
        m = fmaxf(m, dppf<QP_XOR2>(m));
        float esum = 0.f, e2 = 0.f, elab = 0.f;
        #pragma unroll
        for (int i = 0; i < 5; ++i) {
            float e = __expf(cv[i] - m);
            esum += e; e2 += e * e;
            if (q * 5 + i == lab) elab = e;
        }
        esum += dppf<QP_XOR1>(esum);  esum += dppf<QP_XOR2>(esum);
        e2   += dppf<QP_XOR1>(e2);    e2   += dppf<QP_XOR2>(e2);
        elab += dppf<QP_XOR1>(elab);  elab += dppf<QP_XOR2>(elab);
        if (q == 0) {
            float inv = 1.0f / esum;
            contrib += e2 * inv * inv - 2.0f * elab * inv + 1.0f;
        }
    }

    // per-lane fold: division by wave-uniform (98-mc) distributes over the sum
    const float invDen = 1.0f / (98.0f - (float)mc);
    return contrib + LNf * (ns - ms) * invDen;
}

// 128 threads = 2 fully independent waves; wave w owns image bid*2+w.
// Wave-local staging + wave-local vmcnt waits; NO barriers at all.
__global__ __launch_bounds__(128) void yolo_loss_kernel(
    const float* __restrict__ outputs,
    const float* __restrict__ boxes,
    const int*   __restrict__ labels,
    float*       __restrict__ per_img)
{
    const int tid  = threadIdx.x;
    const int wave = tid >> 6;
    const int lane = tid & 63;
    const int t    = lane >> 2;      // target 0..15
    const int q    = lane & 3;       // quad role
    const int n    = blockIdx.x * 2 + wave;   // parity(n) == parity(wave)

    __shared__ __align__(16) float s_img[2 * IMGF];  // 11760 B
    __shared__ unsigned char       s_m[2][112];

    // target data loads (anywhere in the VMEM queue; wait math tolerates it)
    const float4 bx = reinterpret_cast<const float4*>(boxes)[(size_t)n * 16 + t];
    const int   lab = labels[(size_t)n * 16 + t] - 1;

    // ---- wave-local staging: 7 insts, parity-split for 16B alignment ----
    const float* gsrc = outputs + (size_t)n * IMGF;
    char* wbase = (char*)&s_img[wave * IMGF];
    const int odd = wave & 1;
    {
        const float* sgp = odd ? gsrc : (gsrc + IMGF - 2);
        char*        slp = odd ? wbase : (wbase + (size_t)(IMGF - 2) * 4);
        if (lane < 2) {
            __builtin_amdgcn_global_load_lds((const AS1 void*)(sgp + lane),
                                             (AS3 void*)slp, 4, 0, 0);
        }
        const float4* g4 = reinterpret_cast<const float4*>(gsrc + (odd ? 2 : 0));
        char* l4 = wbase + (odd ? 8 : 0);
        #pragma unroll
        for (int k = 0; k < 5; ++k) {
            __builtin_amdgcn_global_load_lds(
                (const AS1 void*)(g4 + k * 64 + lane),
                (AS3 void*)(l4 + (size_t)k * 1024), 16, 0, 0);
        }
        if (lane < 367 - 320) {      // round 5 tail: 47 lanes
            __builtin_amdgcn_global_load_lds(
                (const AS1 void*)(g4 + 320 + lane),
                (AS3 void*)(l4 + (size_t)5 * 1024), 16, 0, 0);
        }
    }

    const float* img = &s_img[wave * IMGF];

    // split wait: in ANY placement of bx/lab, <=2 outstanding => small piece +
    // rounds 0..3 landed => floats 0..959 (cells 0..31) valid; slot=lane OK.
    asm volatile("s_waitcnt vmcnt(2)" ::: "memory");
    __builtin_amdgcn_sched_barrier(0);
    const float cf1 = img[(lane >> 1) * NCH + (lane & 1) * 5 + 4];

    asm volatile("s_waitcnt vmcnt(0)" ::: "memory");
    __builtin_amdgcn_sched_barrier(0);

    float v = img_partial(img, bx, lab, s_m[wave], lane, t, q, cf1);

    // ---- 64-lane reduce fully on VALU: xor1,xor2,ror4,ror8 -> row sums ----
    v += dppf<QP_XOR1>(v);
    v += dppf<QP_XOR2>(v);
    v += dppf<ROW_ROR4>(v);
    v += dppf<ROW_ROR8>(v);
    const float tot = (rlane(v, 0) + rlane(v, 16)) + (rlane(v, 32) + rlane(v, 48));
    if (lane == 0) per_img[n] = tot;
}

__global__ __launch_bounds__(1024) void reduce_mean_kernel(
    const float* __restrict__ per_img, float* __restrict__ out, int N)
{
    __shared__ double sd[16];
    double acc = 0.0;
    const float4* p4 = reinterpret_cast<const float4*>(per_img);
    for (int i = threadIdx.x; i < N / 4; i += 1024) {
        float4 v = p4[i];
        acc += (double)v.x + (double)v.y + (double)v.z + (double)v.w;
    }
    #pragma unroll
    for (int off = 32; off > 0; off >>= 1) acc += __shfl_xor(acc, off);
    if ((threadIdx.x & 63) == 0) sd[threadIdx.x >> 6] = acc;
    __syncthreads();
    if (threadIdx.x == 0) {
        double tsum = 0.0;
        #pragma unroll
        for (int w = 0; w < 16; ++w) tsum += sd[w];
        out[0] = (float)(tsum / (double)N);
    }
}

extern "C" void kernel_launch(void* const* d_in, const int* in_sizes, int n_in,
                              void* d_out, int out_size, void* d_ws, size_t ws_size,
                              hipStream_t stream) {
    const float* outputs = (const float*)d_in[0];
    const float* boxes   = (const float*)d_in[1];
    const int*   labels  = (const int*)d_in[2];
    float* out = (float*)d_out;

    const int N  = in_sizes[0] / IMGF;  // 16384 images
    const int nb = N / 2;               // 8192 blocks, 1 image per wave
    float* per_img = (float*)d_ws;      // N floats

    yolo_loss_kernel<<<nb, 128, 0, stream>>>(outputs, boxes, labels, per_img);
    reduce_mean_kernel<<<1, 1024, 0, stream>>>(per_img, out, N);
}